// Round 6
// baseline (1254.421 us; speedup 1.0000x reference)
//
#include <hip/hip_runtime.h>
#include <stdint.h>

#define B_DIM 8
#define S_DIM 4096
#define F_DIM 512
#define H_DIM 2048
#define W_DIM 16
#define L_DIM 4081               // S - W + 1
#define M_TOT 32648              // B * L
#define K1_DIM 8192              // W * F
#define SXF 2097152              // S * F

typedef __bf16 bf16x8 __attribute__((ext_vector_type(8)));
typedef float f32x16 __attribute__((ext_vector_type(16)));

__device__ __forceinline__ unsigned short f2bf(float f) {
  union { float f; uint32_t u; } a; a.f = f;
  return (unsigned short)((a.u + 0x7fffu + ((a.u >> 16) & 1u)) >> 16);
}

__device__ __forceinline__ void async16(const void* g, void* l) {
  __builtin_amdgcn_global_load_lds(
      (__attribute__((address_space(1))) void*)(uintptr_t)g,
      (__attribute__((address_space(3))) void*)l, 16, 0, 0);
}

#define SBAR   __builtin_amdgcn_s_barrier()
#define SCHED0 __builtin_amdgcn_sched_barrier(0)
#define PRIO1  __builtin_amdgcn_s_setprio(1)
#define PRIO0  __builtin_amdgcn_s_setprio(0)
#define VM0    asm volatile("s_waitcnt vmcnt(0)" ::: "memory")

#define MF(A, B, C) __builtin_amdgcn_mfma_f32_32x32x16_bf16(A, B, C, 0, 0, 0)

// read one k-step group into bank X / bank Y: 4 A-frags + 2 B-frags
#define RDX(S) \
  xa0 = *(const bf16x8*)(p + aoffS[S]);         xa1 = *(const bf16x8*)(p + aoffS[S] + 4096); \
  xa2 = *(const bf16x8*)(p + aoffS[S] + 8192);  xa3 = *(const bf16x8*)(p + aoffS[S] + 12288); \
  xb0 = *(const bf16x8*)(p + boffS[S]);         xb1 = *(const bf16x8*)(p + boffS[S] + 4096);
#define RDY(S) \
  ya0 = *(const bf16x8*)(p + aoffS[S]);         ya1 = *(const bf16x8*)(p + aoffS[S] + 4096); \
  ya2 = *(const bf16x8*)(p + aoffS[S] + 8192);  ya3 = *(const bf16x8*)(p + aoffS[S] + 12288); \
  yb0 = *(const bf16x8*)(p + boffS[S]);         yb1 = *(const bf16x8*)(p + boffS[S] + 4096);

// 8 independent 32x32x16 MFMAs (one k-step, full 128x64 wave tile)
#define MFX \
  acc[0][0] = MF(xa0, xb0, acc[0][0]); acc[0][1] = MF(xa0, xb1, acc[0][1]); \
  acc[1][0] = MF(xa1, xb0, acc[1][0]); acc[1][1] = MF(xa1, xb1, acc[1][1]); \
  acc[2][0] = MF(xa2, xb0, acc[2][0]); acc[2][1] = MF(xa2, xb1, acc[2][1]); \
  acc[3][0] = MF(xa3, xb0, acc[3][0]); acc[3][1] = MF(xa3, xb1, acc[3][1]);
#define MFY \
  acc[0][0] = MF(ya0, yb0, acc[0][0]); acc[0][1] = MF(ya0, yb1, acc[0][1]); \
  acc[1][0] = MF(ya1, yb0, acc[1][0]); acc[1][1] = MF(ya1, yb1, acc[1][1]); \
  acc[2][0] = MF(ya2, yb0, acc[2][0]); acc[2][1] = MF(ya2, yb1, acc[2][1]); \
  acc[3][0] = MF(ya3, yb0, acc[3][0]); acc[3][1] = MF(ya3, yb1, acc[3][1]);

// ---------------- GEMM1: h = relu(x_hankel @ w1 + b1) ----------------------
// 256x256 tile, BK=64, 8 waves (2M x 4N, each 128x64). r3/r4 staging,
// swizzle and 1-sync/K-tile schedule kept verbatim (best measured, 990us).
// Change: 32x32x16 MFMA (pipe 2495 vs 2176 TF measured -> MFMA content
// -13%; HALF the MFMA instruction count -> half the matrix-pipe issue
// occupancy per wave) + 4-stage s-pipeline inside the tile: read-group
// s+1 issues between MFMA-groups using two register banks, no barriers,
// so read/MFMA interleave happens at wave level (r1/r2/r5 showed
// barrier-level phase structure is null; per-wave burst alternation is
// the remaining suspect).
// Frag layouts (32x32x16): A/B: row(col)=lane&31, k=(lane>>5)*8+e
// (verified-by-analogy to the working 16x16x32 mapping); C/D:
// col=lane&31, row=(reg&3)+8*(reg>>2)+4*(lane>>5) [m74/m101 verified].
// Swizzle parity: frag rows == lane&7 (mod 8) for every t -> same XOR
// pattern as r3 (0 measured conflicts).
__global__ __launch_bounds__(512, 2) void gemm1_kernel(
    const unsigned short* __restrict__ xb,
    const unsigned short* __restrict__ w1t,
    const float* __restrict__ bias1,
    unsigned short* __restrict__ h)
{
  __shared__ alignas(16) unsigned char lsm[131072];  // [2][A 32K | B 32K]

  const int tid  = threadIdx.x;
  const int lane = tid & 63;
  const int wave = tid >> 6;           // 0..7
  const int id = blockIdx.x;
  const int nt = id & 7;               // XCD-pinned B column
  const int mt = id >> 3;

  // ---- staging decode: thread t covers row rr, 16B slot (t&7),
  //      swizzled global col-group ((t&7) ^ (rr&7)) ----
  const int rr   = tid >> 3;           // 0..63
  const int xoro = (((tid & 7) ^ (rr & 7)) << 3);  // element offset in row

  const unsigned short* pA0; const unsigned short* pA1;
  const unsigned short* pA2; const unsigned short* pA3;
#define MKPA(PS, S) { \
    int m = mt * 256 + (S) * 64 + rr; \
    if (m >= M_TOT) m = M_TOT - 1; \
    const int b_ = m / L_DIM, l_ = m - b_ * L_DIM; \
    PS = xb + (size_t)b_ * SXF + (size_t)l_ * F_DIM + xoro; }
  MKPA(pA0, 0) MKPA(pA1, 1) MKPA(pA2, 2) MKPA(pA3, 3)
#undef MKPA
  const unsigned short* pB0 = w1t + (size_t)(nt * 256 +   0 + rr) * K1_DIM + xoro;
  const unsigned short* pB1 = w1t + (size_t)(nt * 256 +  64 + rr) * K1_DIM + xoro;
  const unsigned short* pB2 = w1t + (size_t)(nt * 256 + 128 + rr) * K1_DIM + xoro;
  const unsigned short* pB3 = w1t + (size_t)(nt * 256 + 192 + rr) * K1_DIM + xoro;

  const int wm = wave >> 2;            // 0..1 : 128-row band
  const int wn = wave & 3;             // 0..3 : 64-col band

  // ---- consumer lane bases (swizzled): frag row = band + (lane&31),
  //      16B slot = (s*2 + lane>>5) ^ (lane&7); +t*4096 walks 32-row tiles
  const int l31 = lane & 31;
  const int e7  = lane & 7;
  const int h5  = lane >> 5;
  int aoffS[4], boffS[4];
#pragma unroll
  for (int s = 0; s < 4; ++s) {
    const int sl = ((s * 2 + h5) ^ e7) << 4;
    aoffS[s] = (wm * 128 + l31) * 128 + sl;
    boffS[s] = 32768 + (wn * 64 + l31) * 128 + sl;
  }

  f32x16 acc[4][2] = {};

  const int KT = K1_DIM / 64;          // 128 K-tiles

#define STAGE_A(TT) { \
    const size_t ko_ = (size_t)(TT) * 64; \
    unsigned char* d_ = lsm + (((TT) & 1) << 16) + tid * 16; \
    async16(pA0 + ko_, d_);         async16(pA1 + ko_, d_ + 8192); \
    async16(pA2 + ko_, d_ + 16384); async16(pA3 + ko_, d_ + 24576); }
#define STAGE_B(TT) { \
    const size_t ko_ = (size_t)(TT) * 64; \
    unsigned char* d_ = lsm + (((TT) & 1) << 16) + 32768 + tid * 16; \
    async16(pB0 + ko_, d_);         async16(pB1 + ko_, d_ + 8192); \
    async16(pB2 + ko_, d_ + 16384); async16(pB3 + ko_, d_ + 24576); }

  // prologue: stage tile 0, wait, go
  STAGE_B(0); STAGE_A(0);
  VM0; SBAR; SCHED0;

  for (int kt = 0; kt < KT; ++kt) {
    const unsigned char* p = lsm + ((kt & 1) << 16);
    bf16x8 xa0, xa1, xa2, xa3, xb0, xb1;
    bf16x8 ya0, ya1, ya2, ya3, yb0, yb1;

    // next-tile stages first: full-tile latency cover (r4, neutral-safe)
    if (kt + 1 < KT) { STAGE_B(kt + 1); STAGE_A(kt + 1); }

    // 4-step s-pipeline, two register banks, no intra-tile barriers
    RDX(0);
    RDY(1);
    PRIO1; MFX; PRIO0;   // s0 compute ∥ s1 reads outstanding
    RDX(2);
    PRIO1; MFY; PRIO0;   // s1 compute ∥ s2 reads outstanding
    RDY(3);
    PRIO1; MFX; PRIO0;   // s2 compute ∥ s3 reads outstanding
    PRIO1; MFY; PRIO0;   // s3 compute

    VM0; SBAR; SCHED0;                         // next tile landed; flip
  }
#undef STAGE_A
#undef STAGE_B

  // C/D (32x32): col = lane&31, row = (reg&3) + 8*(reg>>2) + 4*(lane>>5)
  const int ncol  = nt * 256 + wn * 64 + l31;
  const int mbase = mt * 256 + wm * 128 + 4 * h5;
#pragma unroll
  for (int u = 0; u < 2; ++u) {
    const int n = ncol + u * 32;
    const float bv = bias1[n];
#pragma unroll
    for (int t = 0; t < 4; ++t) {
#pragma unroll
      for (int r = 0; r < 16; ++r) {
        const int m = mbase + t * 32 + (r & 3) + 8 * (r >> 2);
        if (m < M_TOT) {
          float v = acc[t][u][r] + bv;
          v = v > 0.f ? v : 0.f;
          h[(size_t)m * H_DIM + n] = f2bf(v);
        }
      }
    }
  }
}

// ---------------- GEMM2: y = h @ w2 + b2, same structure, KT=32 ------------
__global__ __launch_bounds__(512, 2) void gemm2_kernel(
    const unsigned short* __restrict__ hmat,
    const unsigned short* __restrict__ w2t,   // [512][2048]
    const float* __restrict__ bias2,
    float* __restrict__ out)
{
  __shared__ alignas(16) unsigned char lsm[131072];

  const int tid  = threadIdx.x;
  const int lane = tid & 63;
  const int wave = tid >> 6;
  const int id = blockIdx.x;
  const int nt = id & 1;               // 2 col tiles of 256 (N=512)
  const int mt = id >> 1;

  const int rr   = tid >> 3;
  const int xoro = (((tid & 7) ^ (rr & 7)) << 3);

  const unsigned short* pA0; const unsigned short* pA1;
  const unsigned short* pA2; const unsigned short* pA3;
#define MKPA(PS, S) { \
    int m = mt * 256 + (S) * 64 + rr; \
    if (m >= M_TOT) m = M_TOT - 1; \
    PS = hmat + (size_t)m * H_DIM + xoro; }
  MKPA(pA0, 0) MKPA(pA1, 1) MKPA(pA2, 2) MKPA(pA3, 3)
#undef MKPA
  const unsigned short* pB0 = w2t + (size_t)(nt * 256 +   0 + rr) * H_DIM + xoro;
  const unsigned short* pB1 = w2t + (size_t)(nt * 256 +  64 + rr) * H_DIM + xoro;
  const unsigned short* pB2 = w2t + (size_t)(nt * 256 + 128 + rr) * H_DIM + xoro;
  const unsigned short* pB3 = w2t + (size_t)(nt * 256 + 192 + rr) * H_DIM + xoro;

  const int wm = wave >> 2;
  const int wn = wave & 3;
  const int l31 = lane & 31;
  const int e7  = lane & 7;
  const int h5  = lane >> 5;
  int aoffS[4], boffS[4];
#pragma unroll
  for (int s = 0; s < 4; ++s) {
    const int sl = ((s * 2 + h5) ^ e7) << 4;
    aoffS[s] = (wm * 128 + l31) * 128 + sl;
    boffS[s] = 32768 + (wn * 64 + l31) * 128 + sl;
  }

  f32x16 acc[4][2] = {};

  const int KT = H_DIM / 64;           // 32 K-tiles

#define STAGE_A(TT) { \
    const size_t ko_ = (size_t)(TT) * 64; \
    unsigned char* d_ = lsm + (((TT) & 1) << 16) + tid * 16; \
    async16(pA0 + ko_, d_);         async16(pA1 + ko_, d_ + 8192); \
    async16(pA2 + ko_, d_ + 16384); async16(pA3 + ko_, d_ + 24576); }
#define STAGE_B(TT) { \
    const size_t ko_ = (size_t)(TT) * 64; \
    unsigned char* d_ = lsm + (((TT) & 1) << 16) + 32768 + tid * 16; \
    async16(pB0 + ko_, d_);         async16(pB1 + ko_, d_ + 8192); \
    async16(pB2 + ko_, d_ + 16384); async16(pB3 + ko_, d_ + 24576); }

  STAGE_B(0); STAGE_A(0);
  VM0; SBAR; SCHED0;

  for (int kt = 0; kt < KT; ++kt) {
    const unsigned char* p = lsm + ((kt & 1) << 16);
    bf16x8 xa0, xa1, xa2, xa3, xb0, xb1;
    bf16x8 ya0, ya1, ya2, ya3, yb0, yb1;

    if (kt + 1 < KT) { STAGE_B(kt + 1); STAGE_A(kt + 1); }

    RDX(0);
    RDY(1);
    PRIO1; MFX; PRIO0;
    RDX(2);
    PRIO1; MFY; PRIO0;
    RDY(3);
    PRIO1; MFX; PRIO0;
    PRIO1; MFY; PRIO0;

    VM0; SBAR; SCHED0;
  }
#undef STAGE_A
#undef STAGE_B

  const int ncol  = nt * 256 + wn * 64 + l31;
  const int mbase = mt * 256 + wm * 128 + 4 * h5;
#pragma unroll
  for (int u = 0; u < 2; ++u) {
    const int n = ncol + u * 32;
    const float bv = bias2[n];
#pragma unroll
    for (int t = 0; t < 4; ++t) {
#pragma unroll
      for (int r = 0; r < 16; ++r) {
        const int m = mbase + t * 32 + (r & 3) + 8 * (r >> 2);
        if (m < M_TOT) {
          const int b = m / L_DIM;
          const int l = m - b * L_DIM;
          out[(size_t)b * SXF + (size_t)l * F_DIM + n] = acc[t][u][r] + bv;
        }
      }
    }
  }
}

// ---------------- conversion / transpose / pad helpers ----------------------
__global__ void cvt_bf16_kernel(const float* __restrict__ in,
                                unsigned short* __restrict__ out, int n4) {
  int idx = blockIdx.x * 256 + threadIdx.x;
  if (idx < n4) {
    float4 v = ((const float4*)in)[idx];
    ushort4 o;
    o.x = f2bf(v.x); o.y = f2bf(v.y); o.z = f2bf(v.z); o.w = f2bf(v.w);
    ((ushort4*)out)[idx] = o;
  }
}

// out[c][r] = bf16(in[r][c]); R, C multiples of 64
__global__ void transpose_cvt_kernel(const float* __restrict__ in,
                                     unsigned short* __restrict__ out, int R, int C) {
  __shared__ unsigned short tile[64][72];
  const int tx = threadIdx.x & 15;
  const int ty = threadIdx.x >> 4;
  const int r0 = blockIdx.x * 64;
  const int c0 = blockIdx.y * 64;
#pragma unroll
  for (int i = 0; i < 4; ++i) {
    const int r = r0 + ty + i * 16;
    float4 v = *(const float4*)(in + (size_t)r * C + c0 + tx * 4);
    tile[ty + i * 16][tx * 4 + 0] = f2bf(v.x);
    tile[ty + i * 16][tx * 4 + 1] = f2bf(v.y);
    tile[ty + i * 16][tx * 4 + 2] = f2bf(v.z);
    tile[ty + i * 16][tx * 4 + 3] = f2bf(v.w);
  }
  __syncthreads();
#pragma unroll
  for (int i = 0; i < 4; ++i) {
    const int c = c0 + ty + i * 16;
    ushort4 o;
    o.x = tile[tx * 4 + 0][ty + i * 16];
    o.y = tile[tx * 4 + 1][ty + i * 16];
    o.z = tile[tx * 4 + 2][ty + i * 16];
    o.w = tile[tx * 4 + 3][ty + i * 16];
    *(ushort4*)(out + (size_t)c * R + r0 + tx * 4) = o;
  }
}

__global__ void zero_pad_kernel(float* __restrict__ out) {
  int idx = blockIdx.x * 256 + threadIdx.x;          // 8 * 15 * 128 float4s
  if (idx < B_DIM * 15 * 128) {
    int b = idx / (15 * 128);
    int rem = idx - b * (15 * 128);
    int l = L_DIM + rem / 128;
    int f4 = rem - (rem / 128) * 128;
    ((float4*)out)[(size_t)b * (SXF / 4) + (size_t)l * 128 + f4] =
        make_float4(0.f, 0.f, 0.f, 0.f);
  }
}

__global__ void fill_sentinel(float* out, int n) {   // distinctive ws-too-small marker
  int idx = blockIdx.x * 256 + threadIdx.x;
  if (idx < n) out[idx] = 12345.0f;
}

extern "C" void kernel_launch(void* const* d_in, const int* in_sizes, int n_in,
                              void* d_out, int out_size, void* d_ws, size_t ws_size,
                              hipStream_t stream) {
  const float* x  = (const float*)d_in[0];
  const float* w1 = (const float*)d_in[1];
  const float* b1 = (const float*)d_in[2];
  const float* w2 = (const float*)d_in[3];
  const float* b2 = (const float*)d_in[4];
  float* out = (float*)d_out;

  const size_t OFF_H   = 0;                               // 32648*2048*2 = 133726208
  const size_t OFF_XB  = 133726208;                       // 16777216*2   = 33554432
  const size_t OFF_W1T = OFF_XB + 33554432;               // 8192*2048*2  = 33554432
  const size_t OFF_W2T = OFF_W1T + 33554432;              // 2048*512*2   = 2097152
  const size_t WS_NEED = OFF_W2T + 2097152;               // ~202.9 MB

  if (ws_size < WS_NEED) {
    fill_sentinel<<<65536, 256, 0, stream>>>(out, out_size);
    return;
  }

  unsigned short* hbuf = (unsigned short*)((char*)d_ws + OFF_H);
  unsigned short* xb   = (unsigned short*)((char*)d_ws + OFF_XB);
  unsigned short* w1t  = (unsigned short*)((char*)d_ws + OFF_W1T);
  unsigned short* w2t  = (unsigned short*)((char*)d_ws + OFF_W2T);

  cvt_bf16_kernel<<<16384, 256, 0, stream>>>(x, xb, 4194304);
  transpose_cvt_kernel<<<dim3(128, 32), 256, 0, stream>>>(w1, w1t, 8192, 2048);
  transpose_cvt_kernel<<<dim3(32, 8), 256, 0, stream>>>(w2, w2t, 2048, 512);
  gemm1_kernel<<<1024, 512, 0, stream>>>(xb, w1t, b1, hbuf);
  gemm2_kernel<<<256, 512, 0, stream>>>(hbuf, w2t, b2, out);
  zero_pad_kernel<<<60, 256, 0, stream>>>(out);
}